// Round 1
// baseline (56.763 us; speedup 1.0000x reference)
//
#include <hip/hip_runtime.h>

// out[b][v][p][i][s] = shell[s]*sh[i] / norm[b][l(i)][s]
// B=8 V=2048 P=32 I=16 S=4, monoms=20

__device__ __forceinline__ void compute_monoms(float nx, float ny, float nz, float* m) {
    float zp2 = nz*nz, zp3 = zp2*nz;
    float yp2 = ny*ny, yp3 = yp2*ny;
    float xp2 = nx*nx, xp3 = xp2*nx;
    // sorted (i,j,k), i+j+k<=3, exponents on (nx,ny,nz)
    m[0]=1.0f;  m[1]=nz;       m[2]=zp2;      m[3]=zp3;
    m[4]=ny;    m[5]=ny*nz;    m[6]=ny*zp2;
    m[7]=yp2;   m[8]=yp2*nz;   m[9]=yp3;
    m[10]=nx;   m[11]=nx*nz;   m[12]=nx*zp2;
    m[13]=nx*ny; m[14]=nx*ny*nz; m[15]=nx*yp2;
    m[16]=xp2;  m[17]=xp2*nz;  m[18]=xp2*ny;
    m[19]=xp3;
}

__device__ __forceinline__ void compute_shells(float dist, float* sl) {
    float den = 0.f;
#pragma unroll
    for (int s = 0; s < 4; ++s) {
        float d = dist - (float)s * (1.0f/3.0f);
        sl[s] = __expf(-16.0f * d * d);
        den += sl[s];
    }
    float r = 1.0f / fmaxf(den, 1e-6f);
    float mask = (dist <= 1.0f) ? r : 0.0f;   // zero outside unit ball (after normalize)
#pragma unroll
    for (int s = 0; s < 4; ++s) sl[s] *= mask;
}

// ---------------- Pass 1: ml[b,v,l,s] = sqrt(sum_{i in l} sum_p (sh*shell)^2) ----------------
// 8 units per block (256 thr = 4 waves, 2 units/wave). unit = (b,v).
__global__ __launch_bounds__(256) void sh_pass1(const float* __restrict__ patches,
                                                const float* __restrict__ Y,
                                                float* __restrict__ ml_ws) {
    __shared__ float sh2_lds[8][32][17];   // stride 17: conflict-free scalar writes
    __shared__ float shl2_lds[8][32][5];
    __shared__ float l2_lds[8][16][4];

    const int tid  = threadIdx.x;
    const int wv   = tid >> 6;
    const int lane = tid & 63;
    const int half = lane >> 5;
    const int p    = lane & 31;
    const int u    = wv * 2 + half;          // local unit 0..7
    const int unit = blockIdx.x * 8 + u;     // 0..16383

    // ---- compute phase: lane <-> point ----
    const float* pp = patches + ((size_t)unit * 32 + p) * 3;
    float x = pp[0], y = pp[1], z = pp[2];
    float dist = sqrtf(x*x + y*y + z*z);
    float inv  = 1.0f / fmaxf(dist, 1e-6f);
    float nx = -x*inv, ny = -y*inv, nz = -z*inv;
    float m[20];
    compute_monoms(nx, ny, nz, m);

#pragma unroll
    for (int i = 0; i < 16; ++i) {
        float acc = 0.f;
#pragma unroll
        for (int j = 0; j < 20; ++j)
            acc = fmaf(Y[i*20 + j], m[j], acc);   // uniform -> s_load
        sh2_lds[u][p][i] = acc * acc;
    }
    float sl[4];
    compute_shells(dist, sl);
#pragma unroll
    for (int s = 0; s < 4; ++s) shl2_lds[u][p][s] = sl[s]*sl[s];
    __syncthreads();

    // ---- reduce phase: lane <-> (i,s), 2 units per wave ----
    const int ri = lane >> 2, rs = lane & 3;
    const int u0 = wv*2, u1 = wv*2 + 1;
    float acc0 = 0.f, acc1 = 0.f;
#pragma unroll
    for (int q = 0; q < 32; ++q) {
        acc0 = fmaf(sh2_lds[u0][q][ri], shl2_lds[u0][q][rs], acc0);
        acc1 = fmaf(sh2_lds[u1][q][ri], shl2_lds[u1][q][rs], acc1);
    }
    l2_lds[u0][ri][rs] = acc0;
    l2_lds[u1][ri][rs] = acc1;
    __syncthreads();

    // ---- group-sum over i within each l, sqrt, write ----
    if (lane < 32) {
        const int h2 = lane >> 4;
        const int c  = lane & 15;            // c = l*4 + s
        const int l  = c >> 2, s = c & 3;
        const int uu = wv*2 + h2;
        const int start = l*l, cnt = 2*l + 1;
        float acc = 0.f;
        for (int t = 0; t < cnt; ++t) acc += l2_lds[uu][start + t][s];
        const int gu = blockIdx.x*8 + uu;
        ml_ws[(size_t)gu*16 + c] = sqrtf(acc);
    }
}

// ---------------- Pass 2: rcp_norm[b][c] = 1/max(mean_v ml, 1e-8) ----------------
__global__ __launch_bounds__(256) void sh_pass2(const float* __restrict__ ml_ws,
                                                float* __restrict__ rcp_ws) {
    __shared__ float red[256];
    const int b = blockIdx.x >> 4;
    const int c = blockIdx.x & 15;
    float acc = 0.f;
    for (int v = threadIdx.x; v < 2048; v += 256)
        acc += ml_ws[((size_t)(b*2048 + v))*16 + c];
    red[threadIdx.x] = acc;
    __syncthreads();
    for (int st = 128; st > 0; st >>= 1) {
        if (threadIdx.x < st) red[threadIdx.x] += red[threadIdx.x + st];
        __syncthreads();
    }
    if (threadIdx.x == 0) {
        float meanv = red[0] * (1.0f/2048.0f);
        rcp_ws[blockIdx.x] = 1.0f / fmaxf(meanv, 1e-8f);
    }
}

// ---------------- Pass 3: recompute sh_patches, scale, write 134 MB ----------------
// thread <-> (point, i); writes float4 over s. Wave stores 1KB contiguous.
__global__ __launch_bounds__(256) void sh_pass3(const float* __restrict__ patches,
                                                const float* __restrict__ Y,
                                                const float* __restrict__ rcp_ws,
                                                float4* __restrict__ out) {
    const size_t g  = (size_t)blockIdx.x * 256 + threadIdx.x;
    const int    i  = (int)(g & 15);
    const size_t pt = g >> 4;                 // global point 0..524287
    const int    b  = (int)(pt >> 16);        // 2048*32 points per batch

    const float* pp = patches + pt * 3;
    float x = pp[0], y = pp[1], z = pp[2];
    float dist = sqrtf(x*x + y*y + z*z);
    float inv  = 1.0f / fmaxf(dist, 1e-6f);
    float nx = -x*inv, ny = -y*inv, nz = -z*inv;
    float m[20];
    compute_monoms(nx, ny, nz, m);

    // Y row i into registers via float4 (row = 80B, 16B-aligned)
    float yr[20];
    {
        const float4* Y4 = (const float4*)Y;
#pragma unroll
        for (int q = 0; q < 5; ++q) {
            float4 t = Y4[i*5 + q];
            yr[q*4+0]=t.x; yr[q*4+1]=t.y; yr[q*4+2]=t.z; yr[q*4+3]=t.w;
        }
    }
    float sh = 0.f;
#pragma unroll
    for (int j = 0; j < 20; ++j) sh = fmaf(yr[j], m[j], sh);

    float sl[4];
    compute_shells(dist, sl);

    const int l = (i >= 9) ? 3 : ((i >= 4) ? 2 : ((i >= 1) ? 1 : 0));
    const float4 r = ((const float4*)rcp_ws)[b*4 + l];

    float4 o;
    o.x = sh * sl[0] * r.x;
    o.y = sh * sl[1] * r.y;
    o.z = sh * sl[2] * r.z;
    o.w = sh * sl[3] * r.w;
    out[g] = o;
}

extern "C" void kernel_launch(void* const* d_in, const int* in_sizes, int n_in,
                              void* d_out, int out_size, void* d_ws, size_t ws_size,
                              hipStream_t stream) {
    const float* patches = (const float*)d_in[0];   // 8*2048*32*3
    const float* Y       = (const float*)d_in[1];   // 16*20
    float* out = (float*)d_out;                     // 8*2048*32*16*4

    float* ml_ws  = (float*)d_ws;                   // 16384*16 floats = 1 MB
    float* rcp_ws = ml_ws + 16384*16;               // 128 floats

    sh_pass1<<<2048, 256, 0, stream>>>(patches, Y, ml_ws);
    sh_pass2<<<128, 256, 0, stream>>>(ml_ws, rcp_ws);
    sh_pass3<<<32768, 256, 0, stream>>>(patches, Y, rcp_ws, (float4*)out);
}

// Round 3
// 51.441 us; speedup vs baseline: 1.1035x; 1.1035x over previous
//
#include <hip/hip_runtime.h>

typedef float f32x4 __attribute__((ext_vector_type(4)));

// out[b][v][p][i][s] = shell[s]*sh[i] / norm[b][l(i)][s]
// B=8 V=2048 P=32 I=16 S=4, monoms=20

__device__ __forceinline__ void compute_monoms(float nx, float ny, float nz, float* m) {
    float zp2 = nz*nz, zp3 = zp2*nz;
    float yp2 = ny*ny, yp3 = yp2*ny;
    float xp2 = nx*nx, xp3 = xp2*nx;
    // sorted (i,j,k), i+j+k<=3, exponents on (nx,ny,nz)
    m[0]=1.0f;  m[1]=nz;       m[2]=zp2;      m[3]=zp3;
    m[4]=ny;    m[5]=ny*nz;    m[6]=ny*zp2;
    m[7]=yp2;   m[8]=yp2*nz;   m[9]=yp3;
    m[10]=nx;   m[11]=nx*nz;   m[12]=nx*zp2;
    m[13]=nx*ny; m[14]=nx*ny*nz; m[15]=nx*yp2;
    m[16]=xp2;  m[17]=xp2*nz;  m[18]=xp2*ny;
    m[19]=xp3;
}

// shells: exp(-16(d - s/3)^2) normalized, zeroed outside unit ball.
// arg_s = -16*d^2 + (32*s/3)*d - 16*(s/3)^2  -> fma + __expf
__device__ __forceinline__ void compute_shells(float dist, float* sl) {
    const float B1 = 32.0f/3.0f, B2 = 64.0f/3.0f, B3 = 32.0f;
    const float C1 = -16.0f/9.0f, C2 = -64.0f/9.0f, C3 = -16.0f;
    float nd2 = -16.0f * dist * dist;
    sl[0] = __expf(nd2);
    sl[1] = __expf(fmaf(B1, dist, nd2 + C1));
    sl[2] = __expf(fmaf(B2, dist, nd2 + C2));
    sl[3] = __expf(fmaf(B3, dist, nd2 + C3));
    float den = sl[0] + sl[1] + sl[2] + sl[3];
    float r = 1.0f / fmaxf(den, 1e-6f);
    float mask = (dist <= 1.0f) ? r : 0.0f;
#pragma unroll
    for (int s = 0; s < 4; ++s) sl[s] *= mask;
}

// ---------------- Pass 1: ml[b,v,l,s] = sqrt(sum_{i in l} sum_p (sh*shell)^2) ----------------
// 8 units per block (256 thr = 4 waves, 2 units/wave). unit = (b,v).
__global__ __launch_bounds__(256) void sh_pass1(const float* __restrict__ patches,
                                                const float* __restrict__ Y,
                                                float* __restrict__ ml_ws) {
    __shared__ float sh2_lds[8][32][17];   // stride 17: conflict-free scalar writes
    __shared__ float shl2_lds[8][32][5];
    __shared__ float l2_lds[8][16][4];

    const int tid  = threadIdx.x;
    const int wv   = tid >> 6;
    const int lane = tid & 63;
    const int half = lane >> 5;
    const int p    = lane & 31;
    const int u    = wv * 2 + half;          // local unit 0..7
    const int unit = blockIdx.x * 8 + u;     // 0..16383

    // ---- compute phase: lane <-> point ----
    const float* pp = patches + ((size_t)unit * 32 + p) * 3;
    float x = pp[0], y = pp[1], z = pp[2];
    float dist = sqrtf(x*x + y*y + z*z);
    float inv  = 1.0f / fmaxf(dist, 1e-6f);
    float nx = -x*inv, ny = -y*inv, nz = -z*inv;
    float m[20];
    compute_monoms(nx, ny, nz, m);

#pragma unroll
    for (int i = 0; i < 16; ++i) {
        float acc = 0.f;
#pragma unroll
        for (int j = 0; j < 20; ++j)
            acc = fmaf(Y[i*20 + j], m[j], acc);   // uniform -> s_load
        sh2_lds[u][p][i] = acc * acc;
    }
    float sl[4];
    compute_shells(dist, sl);
#pragma unroll
    for (int s = 0; s < 4; ++s) shl2_lds[u][p][s] = sl[s]*sl[s];
    __syncthreads();

    // ---- reduce phase: lane <-> (i,s), 2 units per wave ----
    const int ri = lane >> 2, rs = lane & 3;
    const int u0 = wv*2, u1 = wv*2 + 1;
    float acc0 = 0.f, acc1 = 0.f;
#pragma unroll
    for (int q = 0; q < 32; ++q) {
        acc0 = fmaf(sh2_lds[u0][q][ri], shl2_lds[u0][q][rs], acc0);
        acc1 = fmaf(sh2_lds[u1][q][ri], shl2_lds[u1][q][rs], acc1);
    }
    l2_lds[u0][ri][rs] = acc0;
    l2_lds[u1][ri][rs] = acc1;
    __syncthreads();

    // ---- group-sum over i within each l, sqrt, write ----
    if (lane < 32) {
        const int h2 = lane >> 4;
        const int c  = lane & 15;            // c = l*4 + s
        const int l  = c >> 2, s = c & 3;
        const int uu = wv*2 + h2;
        const int start = l*l, cnt = 2*l + 1;
        float acc = 0.f;
        for (int t = 0; t < cnt; ++t) acc += l2_lds[uu][start + t][s];
        const int gu = blockIdx.x*8 + uu;
        ml_ws[(size_t)gu*16 + c] = sqrtf(acc);
    }
}

// ---------------- Pass 2: rcp_norm[b][c] = 1/max(mean_v ml, 1e-8) ----------------
__global__ __launch_bounds__(256) void sh_pass2(const float* __restrict__ ml_ws,
                                                float* __restrict__ rcp_ws) {
    __shared__ float red[256];
    const int b = blockIdx.x >> 4;
    const int c = blockIdx.x & 15;
    float acc = 0.f;
    for (int v = threadIdx.x; v < 2048; v += 256)
        acc += ml_ws[((size_t)(b*2048 + v))*16 + c];
    red[threadIdx.x] = acc;
    __syncthreads();
    for (int st = 128; st > 0; st >>= 1) {
        if (threadIdx.x < st) red[threadIdx.x] += red[threadIdx.x + st];
        __syncthreads();
    }
    if (threadIdx.x == 0) {
        float meanv = red[0] * (1.0f/2048.0f);
        rcp_ws[blockIdx.x] = 1.0f / fmaxf(meanv, 1e-8f);
    }
}

// ---------------- Pass 3: recompute, scale, write 134 MB ----------------
// thread <-> (point, i0); produces rows i0 and i0+8 -> point math amortized 2x.
// Store pattern per wave: 8 dense 128B segments + complementary fill -> full lines.
__global__ __launch_bounds__(256) void sh_pass3(const float* __restrict__ patches,
                                                const float* __restrict__ Y,
                                                const float* __restrict__ rcp_ws,
                                                f32x4* __restrict__ out) {
    const size_t g  = (size_t)blockIdx.x * 256 + threadIdx.x;   // 4.19M threads
    const int    i0 = (int)(g & 7);
    const size_t pt = g >> 3;                 // global point 0..524287
    const int    b  = (int)(pt >> 16);        // 2048*32 points per batch

    const float* pp = patches + pt * 3;
    float x = pp[0], y = pp[1], z = pp[2];
    float dist = sqrtf(x*x + y*y + z*z);
    float inv  = 1.0f / fmaxf(dist, 1e-6f);
    float nx = -x*inv, ny = -y*inv, nz = -z*inv;
    float m[20];
    compute_monoms(nx, ny, nz, m);

    float sl[4];
    compute_shells(dist, sl);

    // Y rows i0 and i0+8 via float4 (row = 80B, 16B-aligned)
    const float4* Y4 = (const float4*)Y;
    float sh0 = 0.f, sh1 = 0.f;
    {
        float yr0[20], yr1[20];
#pragma unroll
        for (int q = 0; q < 5; ++q) {
            float4 t0 = Y4[i0*5 + q];
            float4 t1 = Y4[(i0+8)*5 + q];
            yr0[q*4+0]=t0.x; yr0[q*4+1]=t0.y; yr0[q*4+2]=t0.z; yr0[q*4+3]=t0.w;
            yr1[q*4+0]=t1.x; yr1[q*4+1]=t1.y; yr1[q*4+2]=t1.z; yr1[q*4+3]=t1.w;
        }
#pragma unroll
        for (int j = 0; j < 20; ++j) {
            sh0 = fmaf(yr0[j], m[j], sh0);
            sh1 = fmaf(yr1[j], m[j], sh1);
        }
    }

    // l(i): i0: 0->0, 1..3->1, 4..7->2 ; i0+8: 8->2, 9..15->3
    const int l0 = (i0 == 0) ? 0 : ((i0 < 4) ? 1 : 2);
    const int l1 = (i0 == 0) ? 2 : 3;
    const float4 r0 = ((const float4*)rcp_ws)[b*4 + l0];
    const float4 r1 = ((const float4*)rcp_ws)[b*4 + l1];

    f32x4 o0, o1;
    o0.x = sh0 * sl[0] * r0.x;  o1.x = sh1 * sl[0] * r1.x;
    o0.y = sh0 * sl[1] * r0.y;  o1.y = sh1 * sl[1] * r1.y;
    o0.z = sh0 * sl[2] * r0.z;  o1.z = sh1 * sl[2] * r1.z;
    o0.w = sh0 * sl[3] * r0.w;  o1.w = sh1 * sl[3] * r1.w;

    __builtin_nontemporal_store(o0, &out[pt*16 + i0]);
    __builtin_nontemporal_store(o1, &out[pt*16 + i0 + 8]);
}

extern "C" void kernel_launch(void* const* d_in, const int* in_sizes, int n_in,
                              void* d_out, int out_size, void* d_ws, size_t ws_size,
                              hipStream_t stream) {
    const float* patches = (const float*)d_in[0];   // 8*2048*32*3
    const float* Y       = (const float*)d_in[1];   // 16*20
    float* out = (float*)d_out;                     // 8*2048*32*16*4

    float* ml_ws  = (float*)d_ws;                   // 16384*16 floats = 1 MB
    float* rcp_ws = ml_ws + 16384*16;               // 128 floats

    sh_pass1<<<2048, 256, 0, stream>>>(patches, Y, ml_ws);
    sh_pass2<<<128, 256, 0, stream>>>(ml_ws, rcp_ws);
    sh_pass3<<<16384, 256, 0, stream>>>(patches, Y, rcp_ws, (f32x4*)out);
}